// Round 2
// baseline (2373.978 us; speedup 1.0000x reference)
//
#include <hip/hip_runtime.h>
#include <hip/hip_fp16.h>
#include <cstdint>

#define CAP 32
#define WAVES 4

typedef __half half_t;

__device__ __forceinline__ float4 ldh4(const half_t* p) {
  uint2 u = *reinterpret_cast<const uint2*>(p);
  __half2 h0 = *reinterpret_cast<const __half2*>(&u.x);
  __half2 h1 = *reinterpret_cast<const __half2*>(&u.y);
  float2 f0 = __half22float2(h0);
  float2 f1 = __half22float2(h1);
  return make_float4(f0.x, f0.y, f1.x, f1.y);
}

__device__ __forceinline__ void sth4(half_t* p, float x, float y, float z, float w) {
  __half2 h0 = __floats2half2_rn(x, y);
  __half2 h1 = __floats2half2_rn(z, w);
  uint2 u;
  u.x = *reinterpret_cast<unsigned int*>(&h0);
  u.y = *reinterpret_cast<unsigned int*>(&h1);
  *reinterpret_cast<uint2*>(p) = u;
}

// ---------------------------------------------------------------- transpose
// in: (256, V) fp32 row-major (f = b*16+c)  ->  out: (V, 256) fp16
__global__ __launch_bounds__(256) void transpose_kernel(
    const float* __restrict__ in, half_t* __restrict__ out, int V) {
  __shared__ float t[32][33];
  const int f0 = blockIdx.y * 32;
  const int v0 = blockIdx.x * 32;
  const int tid = threadIdx.x;
  const int fi = tid >> 5;
  const int vi = tid & 31;
#pragma unroll
  for (int k = 0; k < 4; ++k) {
    int f = fi + 8 * k;
    t[f][vi] = in[(size_t)(f0 + f) * V + (v0 + vi)];
  }
  __syncthreads();
  const int vl = tid >> 5;
  const int fl = tid & 31;
#pragma unroll
  for (int k = 0; k < 4; ++k) {
    int v = vl + 8 * k;
    out[(size_t)(v0 + v) * 256 + (f0 + fl)] = __float2half_rn(t[fl][v]);
  }
}

// ---------------------------------------------------------------- edge table
__global__ __launch_bounds__(256) void fill_kernel(
    const int* __restrict__ src, const int* __restrict__ dst,
    const float* __restrict__ w, int* __restrict__ cursor,
    int2* __restrict__ slots, int E) {
  int e = blockIdx.x * 256 + threadIdx.x;
  if (e >= E) return;
  int d = dst[e];
  int pos = atomicAdd(&cursor[d], 1);
  if (pos < CAP) slots[(size_t)d * CAP + pos] = make_int2(src[e], __float_as_int(w[e]));
}

// ---------------------------------------------------------------- cheb pass
// PASS 1: X1 = lap(G);  O = bias + G@W0 + X1@W1;  D = X1
// PASS 2: X2 = 2*lap(G) - Pv;  O += X2@W2;  D = X2
// PASS 3: X3 = 2*lap(G) - Pv;  O += X3@W3;  epilogue per EPI
// EPI: 0 none, 1 relu+stats, 2 res+relu+stats, 3 res+relu
template <int PASS, int EPI>
__global__ __launch_bounds__(256) void cheb_pass(
    const half_t* __restrict__ G, const half_t* __restrict__ Pv,
    half_t* __restrict__ D, half_t* __restrict__ O,
    const half_t* __restrict__ resid,
    const int2* __restrict__ slots, const int* __restrict__ cnt,
    const float* __restrict__ Wl, const float* __restrict__ bl,
    float* __restrict__ statsBuf, int V) {
  __shared__ float xl[WAVES][272];   // 16*17 per wave, conflict-free
  __shared__ float wl[512];
  const int tid = threadIdx.x;
  if (PASS == 1) {
    wl[tid] = Wl[tid];
    wl[256 + tid] = Wl[256 + tid];
  } else if (PASS == 2) {
    wl[tid] = Wl[512 + tid];
  } else {
    wl[tid] = Wl[768 + tid];
  }
  __syncthreads();
  const int wave = tid >> 6, lane = tid & 63;
  const int v = blockIdx.x * WAVES + wave;
  if (v >= V) return;
  const int f0 = lane << 2;
  int n = cnt[v];
  n = n > CAP ? CAP : n;
  const int2* __restrict__ row = slots + (size_t)v * CAP;
  float4 acc = make_float4(0.f, 0.f, 0.f, 0.f);
  int e = 0;
  for (; e + 2 <= n; e += 2) {
    int2 s0 = row[e];
    int2 s1 = row[e + 1];
    float w0 = __int_as_float(s0.y), w1 = __int_as_float(s1.y);
    float4 a = ldh4(G + (((size_t)s0.x) << 8) + f0);
    float4 b2 = ldh4(G + (((size_t)s1.x) << 8) + f0);
    acc.x = fmaf(w0, a.x, acc.x); acc.y = fmaf(w0, a.y, acc.y);
    acc.z = fmaf(w0, a.z, acc.z); acc.w = fmaf(w0, a.w, acc.w);
    acc.x = fmaf(w1, b2.x, acc.x); acc.y = fmaf(w1, b2.y, acc.y);
    acc.z = fmaf(w1, b2.z, acc.z); acc.w = fmaf(w1, b2.w, acc.w);
  }
  if (e < n) {
    int2 s0 = row[e];
    float w0 = __int_as_float(s0.y);
    float4 a = ldh4(G + (((size_t)s0.x) << 8) + f0);
    acc.x = fmaf(w0, a.x, acc.x); acc.y = fmaf(w0, a.y, acc.y);
    acc.z = fmaf(w0, a.z, acc.z); acc.w = fmaf(w0, a.w, acc.w);
  }
  const size_t rowoff = (((size_t)v) << 8) + f0;
  float4 g = ldh4(G + rowoff);
  float4 xn;
  if (PASS == 1) {
    xn.x = acc.x - g.x; xn.y = acc.y - g.y; xn.z = acc.z - g.z; xn.w = acc.w - g.w;
  } else {
    float4 p = ldh4(Pv + rowoff);
    xn.x = 2.f * (acc.x - g.x) - p.x;
    xn.y = 2.f * (acc.y - g.y) - p.y;
    xn.z = 2.f * (acc.z - g.z) - p.z;
    xn.w = 2.f * (acc.w - g.w) - p.w;
  }
  if (PASS != 3) {
    sth4(D + rowoff, xn.x, xn.y, xn.z, xn.w);
  }
  // ---- epilogue: out accumulation via per-wave LDS row + 16x16 matmul ----
  const int b = lane >> 2;          // batch index of this lane's features
  const int oc = (lane & 3) << 2;   // output-channel base
  float* xw = xl[wave];
  const int sbase = f0 + b;         // padded slot: f + f/16
  float o[4];
  if (PASS == 1) {
    o[0] = bl[oc + 0]; o[1] = bl[oc + 1]; o[2] = bl[oc + 2]; o[3] = bl[oc + 3];
    xw[sbase + 0] = g.x; xw[sbase + 1] = g.y; xw[sbase + 2] = g.z; xw[sbase + 3] = g.w;
    __builtin_amdgcn_wave_barrier();
    const float* xb = xw + b * 17;
#pragma unroll
    for (int i = 0; i < 16; ++i) {
      float xi = xb[i];
      o[0] = fmaf(xi, wl[i * 16 + oc + 0], o[0]);
      o[1] = fmaf(xi, wl[i * 16 + oc + 1], o[1]);
      o[2] = fmaf(xi, wl[i * 16 + oc + 2], o[2]);
      o[3] = fmaf(xi, wl[i * 16 + oc + 3], o[3]);
    }
    __builtin_amdgcn_wave_barrier();
  } else {
    o[0] = o[1] = o[2] = o[3] = 0.f;
  }
  xw[sbase + 0] = xn.x; xw[sbase + 1] = xn.y; xw[sbase + 2] = xn.z; xw[sbase + 3] = xn.w;
  __builtin_amdgcn_wave_barrier();
  {
    const float* xb = xw + b * 17;
    const float* wm = (PASS == 1) ? (wl + 256) : wl;
#pragma unroll
    for (int i = 0; i < 16; ++i) {
      float xi = xb[i];
      o[0] = fmaf(xi, wm[i * 16 + oc + 0], o[0]);
      o[1] = fmaf(xi, wm[i * 16 + oc + 1], o[1]);
      o[2] = fmaf(xi, wm[i * 16 + oc + 2], o[2]);
      o[3] = fmaf(xi, wm[i * 16 + oc + 3], o[3]);
    }
  }
  half_t* op = O + rowoff;
  if (PASS == 1) {
    sth4(op, o[0], o[1], o[2], o[3]);
  } else if (PASS == 2) {
    float4 c4 = ldh4(op);
    sth4(op, o[0] + c4.x, o[1] + c4.y, o[2] + c4.z, o[3] + c4.w);
  } else {
    float4 c4 = ldh4(op);
    o[0] += c4.x; o[1] += c4.y; o[2] += c4.z; o[3] += c4.w;
    if (EPI >= 2) {
      float4 r = ldh4(resid + rowoff);
      o[0] += r.x; o[1] += r.y; o[2] += r.z; o[3] += r.w;
    }
    o[0] = fmaxf(o[0], 0.f); o[1] = fmaxf(o[1], 0.f);
    o[2] = fmaxf(o[2], 0.f); o[3] = fmaxf(o[3], 0.f);
    sth4(op, o[0], o[1], o[2], o[3]);
    if (EPI == 1 || EPI == 2) {
      float s0 = o[0], s1 = o[1], s2 = o[2], s3 = o[3];
      float q0 = o[0] * o[0], q1 = o[1] * o[1], q2 = o[2] * o[2], q3 = o[3] * o[3];
#pragma unroll
      for (int d = 4; d < 64; d <<= 1) {
        s0 += __shfl_xor(s0, d); s1 += __shfl_xor(s1, d);
        s2 += __shfl_xor(s2, d); s3 += __shfl_xor(s3, d);
        q0 += __shfl_xor(q0, d); q1 += __shfl_xor(q1, d);
        q2 += __shfl_xor(q2, d); q3 += __shfl_xor(q3, d);
      }
      if (lane < 4) {
        float* sb = statsBuf + ((blockIdx.x & 63) << 5);
        atomicAdd(&sb[(lane << 2) + 0], s0);
        atomicAdd(&sb[(lane << 2) + 1], s1);
        atomicAdd(&sb[(lane << 2) + 2], s2);
        atomicAdd(&sb[(lane << 2) + 3], s3);
        atomicAdd(&sb[16 + (lane << 2) + 0], q0);
        atomicAdd(&sb[16 + (lane << 2) + 1], q1);
        atomicAdd(&sb[16 + (lane << 2) + 2], q2);
        atomicAdd(&sb[16 + (lane << 2) + 3], q3);
      }
    }
  }
}

// ---------------------------------------------------------------- batch norm
__global__ void bn_finalize(const float* __restrict__ sb,
                            const float* __restrict__ gamma,
                            const float* __restrict__ beta,
                            float* __restrict__ affine, float invN) {
  int c = threadIdx.x;
  if (c >= 16) return;
  float s = 0.f, q = 0.f;
  for (int k = 0; k < 64; ++k) { s += sb[k * 32 + c]; q += sb[k * 32 + 16 + c]; }
  float mean = s * invN;
  float var = q * invN - mean * mean;
  float inv = rsqrtf(var + 1e-5f);
  float A = gamma[c] * inv;
  float B = beta[c] - mean * A;
  affine[c] = A;
  affine[16 + c] = B;
}

__global__ __launch_bounds__(256) void bn_apply(half_t* __restrict__ X,
                                                const float* __restrict__ affine,
                                                size_t NT) {
  size_t i0 = ((size_t)blockIdx.x * 256 + threadIdx.x) * 8;
  size_t stride = (size_t)gridDim.x * 256 * 8;
  float a[8], bb[8];
#pragma unroll
  for (int j = 0; j < 8; ++j) {
    int c = (int)((i0 + j) & 15);
    a[j] = affine[c];
    bb[j] = affine[16 + c];
  }
  for (size_t i = i0; i < NT; i += stride) {
    uint4 u = *reinterpret_cast<uint4*>(X + i);
    __half2* h = reinterpret_cast<__half2*>(&u);
#pragma unroll
    for (int j = 0; j < 4; ++j) {
      float2 f = __half22float2(h[j]);
      f.x = fmaf(a[2 * j], f.x, bb[2 * j]);
      f.y = fmaf(a[2 * j + 1], f.y, bb[2 * j + 1]);
      h[j] = __floats2half2_rn(f.x, f.y);
    }
    *reinterpret_cast<uint4*>(X + i) = u;
  }
}

// ---------------------------------------------------------------- pooling
__global__ __launch_bounds__(256) void pool_kernel(const half_t* __restrict__ X,
                                                   float* __restrict__ part, int V) {
  int t = threadIdx.x;
  float m = -3.402823466e38f;
  for (int v = blockIdx.x; v < V; v += gridDim.x) {
    m = fmaxf(m, __half2float(X[(((size_t)v) << 8) + t]));
  }
  part[blockIdx.x * 256 + t] = m;
}

__global__ __launch_bounds__(256) void pool_finish(const float* __restrict__ part,
                                                   float* __restrict__ out) {
  int t = threadIdx.x;
  float m = -3.402823466e38f;
  for (int k = 0; k < 256; ++k) m = fmaxf(m, part[k * 256 + t]);
  __shared__ float pm[256];
  __shared__ float mx[16], sm[16];
  pm[t] = m;
  __syncthreads();
  if (t < 16) {
    float M = -3.402823466e38f;
    for (int c = 0; c < 16; ++c) M = fmaxf(M, pm[t * 16 + c]);
    float S = 0.f;
    for (int c = 0; c < 16; ++c) S += expf(pm[t * 16 + c] - M);
    mx[t] = M;
    sm[t] = S;
  }
  __syncthreads();
  out[t] = expf(pm[t] - mx[t >> 4]) / sm[t >> 4];
}

// sentinel: written when workspace is too small, so the absmax tells us ws_size
__global__ void sentinel_kernel(float* out, float val) {
  out[threadIdx.x] = val;
}

// ---------------------------------------------------------------- launcher
extern "C" void kernel_launch(void* const* d_in, const int* in_sizes, int n_in,
                              void* d_out, int out_size, void* d_ws, size_t ws_size,
                              hipStream_t stream) {
  const float* x       = (const float*)d_in[0];
  const float* edge_w  = (const float*)d_in[1];
  const float* weights = (const float*)d_in[2];
  const float* biases  = (const float*)d_in[3];
  const float* gamma   = (const float*)d_in[4];
  const float* beta    = (const float*)d_in[5];
  const int*   esrc    = (const int*)d_in[6];
  const int*   edst    = (const int*)d_in[7];

  const int V = in_sizes[0] / 256;
  const int E = in_sizes[1];
  const size_t NT = (size_t)V * 256;

  char* wsp = (char*)d_ws;
  auto carve = [&](size_t bytes) {
    char* p = wsp;
    wsp += (bytes + 255) & ~(size_t)255;
    return p;
  };
  half_t* P[4];
  for (int i = 0; i < 4; ++i) P[i] = (half_t*)carve(NT * sizeof(half_t));
  int2*  slots  = (int2*)carve((size_t)V * CAP * sizeof(int2));
  int*   cursor = (int*)carve((size_t)V * sizeof(int));
  float* stats  = (float*)carve(5 * 64 * 32 * sizeof(float));
  float* affine = (float*)carve(5 * 32 * sizeof(float));
  float* part   = (float*)carve(256 * 256 * sizeof(float));
  size_t needed = (size_t)(wsp - (char*)d_ws);
  if (needed > ws_size) {
    // can't run: report needed MB through the output so the failure is diagnosable
    sentinel_kernel<<<1, 256, 0, stream>>>((float*)d_out, 100.0f + (float)(needed >> 20));
    return;
  }

  hipMemsetAsync(cursor, 0, (size_t)V * sizeof(int), stream);
  hipMemsetAsync(stats, 0, 5 * 64 * 32 * sizeof(float), stream);

  dim3 tg(V / 32, 8, 1);
  transpose_kernel<<<tg, 256, 0, stream>>>(x, P[0], V);
  fill_kernel<<<(E + 255) / 256, 256, 0, stream>>>(esrc, edst, edge_w, cursor, slots, E);

  const int nb = (V + WAVES - 1) / WAVES;
  const float invN = 1.f / (16.f * (float)V);

  half_t *C = P[0], *X = P[1], *Y = P[2], *Z = P[3];
  for (int blk = 0; blk < 3; ++blk) {
    const float* WA = weights + (size_t)(2 * blk) * 1024;
    const float* WB = weights + (size_t)(2 * blk + 1) * 1024;
    const float* bA = biases + (2 * blk) * 16;
    const float* bB = biases + (2 * blk + 1) * 16;
    float* stA = stats + blk * 2048;
    float* afA = affine + blk * 32;
    // --- cheb A (relu + in-block BN) ---
    cheb_pass<1, 0><<<nb, 256, 0, stream>>>(C, nullptr, X, Y, nullptr, slots, cursor, WA, bA, nullptr, V);
    cheb_pass<2, 0><<<nb, 256, 0, stream>>>(X, C, Z, Y, nullptr, slots, cursor, WA, nullptr, nullptr, V);
    cheb_pass<3, 1><<<nb, 256, 0, stream>>>(Z, X, nullptr, Y, nullptr, slots, cursor, WA, nullptr, stA, V);
    bn_finalize<<<1, 16, 0, stream>>>(stA, gamma + blk * 16, beta + blk * 16, afA, invN);
    bn_apply<<<2048, 256, 0, stream>>>(Y, afA, NT);
    // --- cheb B (+residual, relu; inter-block BN for blocks 0,1) ---
    cheb_pass<1, 0><<<nb, 256, 0, stream>>>(Y, nullptr, X, Z, nullptr, slots, cursor, WB, bB, nullptr, V);
    cheb_pass<2, 0><<<nb, 256, 0, stream>>>(X, Y, Y, Z, nullptr, slots, cursor, WB, nullptr, nullptr, V);
    if (blk < 2) {
      float* stI = stats + (3 + blk) * 2048;
      float* afI = affine + (3 + blk) * 32;
      cheb_pass<3, 2><<<nb, 256, 0, stream>>>(Y, X, nullptr, Z, C, slots, cursor, WB, nullptr, stI, V);
      bn_finalize<<<1, 16, 0, stream>>>(stI, gamma + (3 + blk) * 16, beta + (3 + blk) * 16, afI, invN);
      bn_apply<<<2048, 256, 0, stream>>>(Z, afI, NT);
    } else {
      cheb_pass<3, 3><<<nb, 256, 0, stream>>>(Y, X, nullptr, Z, C, slots, cursor, WB, nullptr, nullptr, V);
    }
    // rotate buffers: (C,X,Y,Z) <- (Z, X, C, Y)
    half_t* oC = C; half_t* oY = Y; half_t* oZ = Z;
    C = oZ; Y = oC; Z = oY;
  }
  // final resblock output lives in C after rotation
  pool_kernel<<<256, 256, 0, stream>>>(C, part, V);
  pool_finish<<<1, 256, 0, stream>>>(part, (float*)d_out);
}

// Round 3
// 2278.778 us; speedup vs baseline: 1.0418x; 1.0418x over previous
//
#include <hip/hip_runtime.h>
#include <hip/hip_fp16.h>
#include <cstdint>

#define CAP 32
#define WAVES 4

typedef __half half_t;

__device__ __forceinline__ float4 ldh4(const half_t* p) {
  uint2 u = *reinterpret_cast<const uint2*>(p);
  __half2 h0 = *reinterpret_cast<const __half2*>(&u.x);
  __half2 h1 = *reinterpret_cast<const __half2*>(&u.y);
  float2 f0 = __half22float2(h0);
  float2 f1 = __half22float2(h1);
  return make_float4(f0.x, f0.y, f1.x, f1.y);
}

__device__ __forceinline__ void sth4(half_t* p, float x, float y, float z, float w) {
  __half2 h0 = __floats2half2_rn(x, y);
  __half2 h1 = __floats2half2_rn(z, w);
  uint2 u;
  u.x = *reinterpret_cast<unsigned int*>(&h0);
  u.y = *reinterpret_cast<unsigned int*>(&h1);
  *reinterpret_cast<uint2*>(p) = u;
}

// ---------------------------------------------------------------- transpose
// in: (256, V) fp32 row-major (f = b*16+c)  ->  out: (V, 256) fp16
__global__ __launch_bounds__(256) void transpose_kernel(
    const float* __restrict__ in, half_t* __restrict__ out, int V) {
  __shared__ float t[32][33];
  const int f0 = blockIdx.y * 32;
  const int v0 = blockIdx.x * 32;
  const int tid = threadIdx.x;
  const int fi = tid >> 5;
  const int vi = tid & 31;
#pragma unroll
  for (int k = 0; k < 4; ++k) {
    int f = fi + 8 * k;
    t[f][vi] = in[(size_t)(f0 + f) * V + (v0 + vi)];
  }
  __syncthreads();
  const int vl = tid >> 5;
  const int fl = tid & 31;
#pragma unroll
  for (int k = 0; k < 4; ++k) {
    int v = vl + 8 * k;
    out[(size_t)(v0 + v) * 256 + (f0 + fl)] = __float2half_rn(t[fl][v]);
  }
}

// ---------------------------------------------------------------- edge table
__global__ __launch_bounds__(256) void init_slots(int2* __restrict__ slots, int total) {
  int i = blockIdx.x * 256 + threadIdx.x;
  if (i < total) slots[i] = make_int2(i >> 5, 0);  // self edge, weight 0 (CAP=32)
}

__global__ __launch_bounds__(256) void fill_kernel(
    const int* __restrict__ src, const int* __restrict__ dst,
    const float* __restrict__ w, int* __restrict__ cursor,
    int2* __restrict__ slots, int E) {
  int e = blockIdx.x * 256 + threadIdx.x;
  if (e >= E) return;
  int d = dst[e];
  int pos = atomicAdd(&cursor[d], 1);
  if (pos < CAP) slots[(size_t)d * CAP + pos] = make_int2(src[e], __float_as_int(w[e]));
}

// ---------------------------------------------------------------- cheb pass
// PASS 1: X1 = lap(G);  O = bias + G@W0 + X1@W1;  D = X1
// PASS 2: X2 = 2*lap(G) - Pv;  O += X2@W2;  D = X2
// PASS 3: X3 = 2*lap(G) - Pv;  O += X3@W3;  epilogue per EPI
// EPI: 0 none, 1 relu+stats, 2 res+relu+stats, 3 res+relu
template <int PASS, int EPI>
__global__ __launch_bounds__(256) void cheb_pass(
    const half_t* __restrict__ G, const half_t* __restrict__ Pv,
    half_t* __restrict__ D, half_t* __restrict__ O,
    const half_t* __restrict__ resid,
    const int2* __restrict__ slots, const int* __restrict__ cnt,
    const float* __restrict__ Wl, const float* __restrict__ bl,
    float* __restrict__ statsBuf, int V) {
  __shared__ float xl[WAVES][272];   // 16*17 per wave, conflict-free
  __shared__ float wl[512];
  const int tid = threadIdx.x;
  if (PASS == 1) {
    wl[tid] = Wl[tid];
    wl[256 + tid] = Wl[256 + tid];
  } else if (PASS == 2) {
    wl[tid] = Wl[512 + tid];
  } else {
    wl[tid] = Wl[768 + tid];
  }
  __syncthreads();
  const int wave = tid >> 6, lane = tid & 63;
  const int v = blockIdx.x * WAVES + wave;
  if (v >= V) return;
  const int f0 = lane << 2;
  const size_t rowoff = (((size_t)v) << 8) + f0;

  // issue independent loads first: slot row (cooperative), own row, prev row
  int2 myslot = slots[((size_t)v << 5) + (lane & 31)];   // lane l holds edge l
  float4 g = ldh4(G + rowoff);
  float4 p = make_float4(0.f, 0.f, 0.f, 0.f);
  if (PASS != 1) p = ldh4(Pv + rowoff);

  int n = cnt[v];
  n = n > CAP ? CAP : n;
  int n8 = (n + 7) & ~7;   // padded slots are (self, w=0): safe, L1-warm

  float4 acc = make_float4(0.f, 0.f, 0.f, 0.f);
  for (int base = 0; base < n8; base += 8) {
    const half_t* ap[8];
    float w[8];
#pragma unroll
    for (int j = 0; j < 8; ++j) {
      int s = __shfl(myslot.x, base + j);
      w[j] = __int_as_float(__shfl(myslot.y, base + j));
      ap[j] = G + (((size_t)s) << 8) + f0;
    }
    float4 a[8];
#pragma unroll
    for (int j = 0; j < 8; ++j) a[j] = ldh4(ap[j]);
#pragma unroll
    for (int j = 0; j < 8; ++j) {
      acc.x = fmaf(w[j], a[j].x, acc.x);
      acc.y = fmaf(w[j], a[j].y, acc.y);
      acc.z = fmaf(w[j], a[j].z, acc.z);
      acc.w = fmaf(w[j], a[j].w, acc.w);
    }
  }

  float4 xn;
  if (PASS == 1) {
    xn.x = acc.x - g.x; xn.y = acc.y - g.y; xn.z = acc.z - g.z; xn.w = acc.w - g.w;
  } else {
    xn.x = 2.f * (acc.x - g.x) - p.x;
    xn.y = 2.f * (acc.y - g.y) - p.y;
    xn.z = 2.f * (acc.z - g.z) - p.z;
    xn.w = 2.f * (acc.w - g.w) - p.w;
  }
  if (PASS != 3) {
    sth4(D + rowoff, xn.x, xn.y, xn.z, xn.w);
  }
  // ---- epilogue: out accumulation via per-wave LDS row + 16x16 matmul ----
  const int b = lane >> 2;          // batch index of this lane's features
  const int oc = (lane & 3) << 2;   // output-channel base
  float* xw = xl[wave];
  const int sbase = f0 + b;         // padded slot: f + f/16
  float o[4];
  if (PASS == 1) {
    o[0] = bl[oc + 0]; o[1] = bl[oc + 1]; o[2] = bl[oc + 2]; o[3] = bl[oc + 3];
    xw[sbase + 0] = g.x; xw[sbase + 1] = g.y; xw[sbase + 2] = g.z; xw[sbase + 3] = g.w;
    __builtin_amdgcn_wave_barrier();
    const float* xb = xw + b * 17;
#pragma unroll
    for (int i = 0; i < 16; ++i) {
      float xi = xb[i];
      o[0] = fmaf(xi, wl[i * 16 + oc + 0], o[0]);
      o[1] = fmaf(xi, wl[i * 16 + oc + 1], o[1]);
      o[2] = fmaf(xi, wl[i * 16 + oc + 2], o[2]);
      o[3] = fmaf(xi, wl[i * 16 + oc + 3], o[3]);
    }
    __builtin_amdgcn_wave_barrier();
  } else {
    o[0] = o[1] = o[2] = o[3] = 0.f;
  }
  xw[sbase + 0] = xn.x; xw[sbase + 1] = xn.y; xw[sbase + 2] = xn.z; xw[sbase + 3] = xn.w;
  __builtin_amdgcn_wave_barrier();
  {
    const float* xb = xw + b * 17;
    const float* wm = (PASS == 1) ? (wl + 256) : wl;
#pragma unroll
    for (int i = 0; i < 16; ++i) {
      float xi = xb[i];
      o[0] = fmaf(xi, wm[i * 16 + oc + 0], o[0]);
      o[1] = fmaf(xi, wm[i * 16 + oc + 1], o[1]);
      o[2] = fmaf(xi, wm[i * 16 + oc + 2], o[2]);
      o[3] = fmaf(xi, wm[i * 16 + oc + 3], o[3]);
    }
  }
  half_t* op = O + rowoff;
  if (PASS == 1) {
    sth4(op, o[0], o[1], o[2], o[3]);
  } else if (PASS == 2) {
    float4 c4 = ldh4(op);
    sth4(op, o[0] + c4.x, o[1] + c4.y, o[2] + c4.z, o[3] + c4.w);
  } else {
    float4 c4 = ldh4(op);
    o[0] += c4.x; o[1] += c4.y; o[2] += c4.z; o[3] += c4.w;
    if (EPI >= 2) {
      float4 r = ldh4(resid + rowoff);
      o[0] += r.x; o[1] += r.y; o[2] += r.z; o[3] += r.w;
    }
    o[0] = fmaxf(o[0], 0.f); o[1] = fmaxf(o[1], 0.f);
    o[2] = fmaxf(o[2], 0.f); o[3] = fmaxf(o[3], 0.f);
    sth4(op, o[0], o[1], o[2], o[3]);
    if (EPI == 1 || EPI == 2) {
      float s0 = o[0], s1 = o[1], s2 = o[2], s3 = o[3];
      float q0 = o[0] * o[0], q1 = o[1] * o[1], q2 = o[2] * o[2], q3 = o[3] * o[3];
#pragma unroll
      for (int d = 4; d < 64; d <<= 1) {
        s0 += __shfl_xor(s0, d); s1 += __shfl_xor(s1, d);
        s2 += __shfl_xor(s2, d); s3 += __shfl_xor(s3, d);
        q0 += __shfl_xor(q0, d); q1 += __shfl_xor(q1, d);
        q2 += __shfl_xor(q2, d); q3 += __shfl_xor(q3, d);
      }
      if (lane < 4) {
        float* sb = statsBuf + ((blockIdx.x & 63) << 5);
        atomicAdd(&sb[(lane << 2) + 0], s0);
        atomicAdd(&sb[(lane << 2) + 1], s1);
        atomicAdd(&sb[(lane << 2) + 2], s2);
        atomicAdd(&sb[(lane << 2) + 3], s3);
        atomicAdd(&sb[16 + (lane << 2) + 0], q0);
        atomicAdd(&sb[16 + (lane << 2) + 1], q1);
        atomicAdd(&sb[16 + (lane << 2) + 2], q2);
        atomicAdd(&sb[16 + (lane << 2) + 3], q3);
      }
    }
  }
}

// ---------------------------------------------------------------- batch norm
__global__ void bn_finalize(const float* __restrict__ sb,
                            const float* __restrict__ gamma,
                            const float* __restrict__ beta,
                            float* __restrict__ affine, float invN) {
  int c = threadIdx.x;
  if (c >= 16) return;
  float s = 0.f, q = 0.f;
  for (int k = 0; k < 64; ++k) { s += sb[k * 32 + c]; q += sb[k * 32 + 16 + c]; }
  float mean = s * invN;
  float var = q * invN - mean * mean;
  float inv = rsqrtf(var + 1e-5f);
  float A = gamma[c] * inv;
  float B = beta[c] - mean * A;
  affine[c] = A;
  affine[16 + c] = B;
}

__global__ __launch_bounds__(256) void bn_apply(half_t* __restrict__ X,
                                                const float* __restrict__ affine,
                                                size_t NT) {
  size_t i0 = ((size_t)blockIdx.x * 256 + threadIdx.x) * 8;
  size_t stride = (size_t)gridDim.x * 256 * 8;
  float a[8], bb[8];
#pragma unroll
  for (int j = 0; j < 8; ++j) {
    int c = (int)((i0 + j) & 15);
    a[j] = affine[c];
    bb[j] = affine[16 + c];
  }
  for (size_t i = i0; i < NT; i += stride) {
    uint4 u = *reinterpret_cast<uint4*>(X + i);
    __half2* h = reinterpret_cast<__half2*>(&u);
#pragma unroll
    for (int j = 0; j < 4; ++j) {
      float2 f = __half22float2(h[j]);
      f.x = fmaf(a[2 * j], f.x, bb[2 * j]);
      f.y = fmaf(a[2 * j + 1], f.y, bb[2 * j + 1]);
      h[j] = __floats2half2_rn(f.x, f.y);
    }
    *reinterpret_cast<uint4*>(X + i) = u;
  }
}

// ---------------------------------------------------------------- pooling
__global__ __launch_bounds__(256) void pool_kernel(const half_t* __restrict__ X,
                                                   float* __restrict__ part, int V) {
  int t = threadIdx.x;
  float m = -3.402823466e38f;
  for (int v = blockIdx.x; v < V; v += gridDim.x) {
    m = fmaxf(m, __half2float(X[(((size_t)v) << 8) + t]));
  }
  part[blockIdx.x * 256 + t] = m;
}

__global__ __launch_bounds__(256) void pool_finish(const float* __restrict__ part,
                                                   float* __restrict__ out) {
  int t = threadIdx.x;
  float m = -3.402823466e38f;
  for (int k = 0; k < 256; ++k) m = fmaxf(m, part[k * 256 + t]);
  __shared__ float pm[256];
  __shared__ float mx[16], sm[16];
  pm[t] = m;
  __syncthreads();
  if (t < 16) {
    float M = -3.402823466e38f;
    for (int c = 0; c < 16; ++c) M = fmaxf(M, pm[t * 16 + c]);
    float S = 0.f;
    for (int c = 0; c < 16; ++c) S += expf(pm[t * 16 + c] - M);
    mx[t] = M;
    sm[t] = S;
  }
  __syncthreads();
  out[t] = expf(pm[t] - mx[t >> 4]) / sm[t >> 4];
}

// sentinel: written when workspace is too small, so the absmax tells us ws_size
__global__ void sentinel_kernel(float* out, float val) {
  out[threadIdx.x] = val;
}

// ---------------------------------------------------------------- launcher
extern "C" void kernel_launch(void* const* d_in, const int* in_sizes, int n_in,
                              void* d_out, int out_size, void* d_ws, size_t ws_size,
                              hipStream_t stream) {
  const float* x       = (const float*)d_in[0];
  const float* edge_w  = (const float*)d_in[1];
  const float* weights = (const float*)d_in[2];
  const float* biases  = (const float*)d_in[3];
  const float* gamma   = (const float*)d_in[4];
  const float* beta    = (const float*)d_in[5];
  const int*   esrc    = (const int*)d_in[6];
  const int*   edst    = (const int*)d_in[7];

  const int V = in_sizes[0] / 256;
  const int E = in_sizes[1];
  const size_t NT = (size_t)V * 256;

  char* wsp = (char*)d_ws;
  auto carve = [&](size_t bytes) {
    char* p = wsp;
    wsp += (bytes + 255) & ~(size_t)255;
    return p;
  };
  half_t* P[4];
  for (int i = 0; i < 4; ++i) P[i] = (half_t*)carve(NT * sizeof(half_t));
  int2*  slots  = (int2*)carve((size_t)V * CAP * sizeof(int2));
  int*   cursor = (int*)carve((size_t)V * sizeof(int));
  float* stats  = (float*)carve(5 * 64 * 32 * sizeof(float));
  float* affine = (float*)carve(5 * 32 * sizeof(float));
  float* part   = (float*)carve(256 * 256 * sizeof(float));
  size_t needed = (size_t)(wsp - (char*)d_ws);
  if (needed > ws_size) {
    sentinel_kernel<<<1, 256, 0, stream>>>((float*)d_out, 100.0f + (float)(needed >> 20));
    return;
  }

  hipMemsetAsync(cursor, 0, (size_t)V * sizeof(int), stream);
  hipMemsetAsync(stats, 0, 5 * 64 * 32 * sizeof(float), stream);

  const int totalSlots = V * CAP;
  init_slots<<<(totalSlots + 255) / 256, 256, 0, stream>>>(slots, totalSlots);

  dim3 tg(V / 32, 8, 1);
  transpose_kernel<<<tg, 256, 0, stream>>>(x, P[0], V);
  fill_kernel<<<(E + 255) / 256, 256, 0, stream>>>(esrc, edst, edge_w, cursor, slots, E);

  const int nb = (V + WAVES - 1) / WAVES;
  const float invN = 1.f / (16.f * (float)V);

  half_t *C = P[0], *X = P[1], *Y = P[2], *Z = P[3];
  for (int blk = 0; blk < 3; ++blk) {
    const float* WA = weights + (size_t)(2 * blk) * 1024;
    const float* WB = weights + (size_t)(2 * blk + 1) * 1024;
    const float* bA = biases + (2 * blk) * 16;
    const float* bB = biases + (2 * blk + 1) * 16;
    float* stA = stats + blk * 2048;
    float* afA = affine + blk * 32;
    // --- cheb A (relu + in-block BN) ---
    cheb_pass<1, 0><<<nb, 256, 0, stream>>>(C, nullptr, X, Y, nullptr, slots, cursor, WA, bA, nullptr, V);
    cheb_pass<2, 0><<<nb, 256, 0, stream>>>(X, C, Z, Y, nullptr, slots, cursor, WA, nullptr, nullptr, V);
    cheb_pass<3, 1><<<nb, 256, 0, stream>>>(Z, X, nullptr, Y, nullptr, slots, cursor, WA, nullptr, stA, V);
    bn_finalize<<<1, 16, 0, stream>>>(stA, gamma + blk * 16, beta + blk * 16, afA, invN);
    bn_apply<<<2048, 256, 0, stream>>>(Y, afA, NT);
    // --- cheb B (+residual, relu; inter-block BN for blocks 0,1) ---
    cheb_pass<1, 0><<<nb, 256, 0, stream>>>(Y, nullptr, X, Z, nullptr, slots, cursor, WB, bB, nullptr, V);
    cheb_pass<2, 0><<<nb, 256, 0, stream>>>(X, Y, Y, Z, nullptr, slots, cursor, WB, nullptr, nullptr, V);
    if (blk < 2) {
      float* stI = stats + (3 + blk) * 2048;
      float* afI = affine + (3 + blk) * 32;
      cheb_pass<3, 2><<<nb, 256, 0, stream>>>(Y, X, nullptr, Z, C, slots, cursor, WB, nullptr, stI, V);
      bn_finalize<<<1, 16, 0, stream>>>(stI, gamma + (3 + blk) * 16, beta + (3 + blk) * 16, afI, invN);
      bn_apply<<<2048, 256, 0, stream>>>(Z, afI, NT);
    } else {
      cheb_pass<3, 3><<<nb, 256, 0, stream>>>(Y, X, nullptr, Z, C, slots, cursor, WB, nullptr, nullptr, V);
    }
    // rotate buffers: (C,X,Y,Z) <- (Z, X, C, Y)
    half_t* oC = C; half_t* oY = Y; half_t* oZ = Z;
    C = oZ; Y = oC; Z = oY;
  }
  // final resblock output lives in C after rotation
  pool_kernel<<<256, 256, 0, stream>>>(C, part, V);
  pool_finish<<<1, 256, 0, stream>>>(part, (float*)d_out);
}